// Round 1
// baseline (98967.041 us; speedup 1.0000x reference)
//
#include <hip/hip_runtime.h>
#include <hip/hip_cooperative_groups.h>
#include <math.h>

namespace cg = cooperative_groups;

#define BB 32
#define TT 1000
#define HH 512
#define JJ 512
#define VV 1024
#define G4 2048

// ---- persistent device-side scratch (static: independent of ws_size, graph-safe) ----
__device__ __align__(16) float g_encp[(size_t)TT * JJ * BB];  // [t][j][b]  65.5 MB
__device__ __align__(16) float g_E[(size_t)VV * G4];          // [v][g] = embed @ W_ih, 8 MB
__device__ __align__(16) float g_outPN[HH * BB];              // [k][b]
__device__ __align__(16) float g_h[HH * BB];                  // [k][b]
__device__ __align__(16) float g_c[BB * HH];                  // [b][k]
__device__ __align__(16) float g_joint[JJ * BB];              // [j][b]
__device__ __align__(16) float g_hW[BB * G4];                 // [b][g] = h @ W_hh
__device__ float g_pmax[BB * 64];
__device__ float g_psum[BB * 64];
__device__ int   g_parg[BB * 64];
__device__ float g_score[BB];

// ---------------- K0: enc_proj[t][j][b] = sum_k enc[b][t][k] * W_enc[k][j] ----------------
__global__ __launch_bounds__(256) void k_encproj(const float* __restrict__ enc,
                                                 const float* __restrict__ Wenc) {
    __shared__ __align__(16) float x[BB * 512];   // [b][k] 64KB
    const int t = blockIdx.x;
    for (int i = threadIdx.x; i < BB * 128; i += 256) {
        const int b = i >> 7, k4 = i & 127;
        *reinterpret_cast<float4*>(x + b * 512 + k4 * 4) =
            *reinterpret_cast<const float4*>(enc + ((size_t)(b * TT + t)) * 512 + k4 * 4);
    }
    __syncthreads();
    const int j = threadIdx.x;   // columns j and j+256
    float acc0[BB], acc1[BB];
#pragma unroll
    for (int b = 0; b < BB; ++b) { acc0[b] = 0.f; acc1[b] = 0.f; }
    for (int k4 = 0; k4 < 128; ++k4) {
        const int k = k4 * 4;
        float w0[4], w1[4];
#pragma unroll
        for (int i = 0; i < 4; ++i) {
            w0[i] = Wenc[(size_t)(k + i) * JJ + j];
            w1[i] = Wenc[(size_t)(k + i) * JJ + j + 256];
        }
#pragma unroll
        for (int b = 0; b < BB; ++b) {
            const float4 xv = *reinterpret_cast<const float4*>(x + b * 512 + k);
            acc0[b] += xv.x * w0[0] + xv.y * w0[1] + xv.z * w0[2] + xv.w * w0[3];
            acc1[b] += xv.x * w1[0] + xv.y * w1[1] + xv.z * w1[2] + xv.w * w1[3];
        }
    }
    float* outt = g_encp + (size_t)t * JJ * BB;
#pragma unroll
    for (int b = 0; b < BB; ++b) {
        outt[j * BB + b]         = acc0[b];
        outt[(j + 256) * BB + b] = acc1[b];
    }
}

// ---------------- K1: E[v][g] = sum_k embed[v][k] * W_ih[k][g] ----------------
__global__ __launch_bounds__(256) void k_embproj(const float* __restrict__ emb,
                                                 const float* __restrict__ Wih) {
    __shared__ __align__(16) float x[BB * 512];
    const int v0 = (blockIdx.x >> 2) * 32;
    const int g0 = (blockIdx.x & 3) * 512;
    for (int i = threadIdx.x; i < BB * 128; i += 256) {
        const int b = i >> 7, k4 = i & 127;
        *reinterpret_cast<float4*>(x + b * 512 + k4 * 4) =
            *reinterpret_cast<const float4*>(emb + (size_t)(v0 + b) * 512 + k4 * 4);
    }
    __syncthreads();
    const int j = g0 + threadIdx.x;
    float acc0[BB], acc1[BB];
#pragma unroll
    for (int b = 0; b < BB; ++b) { acc0[b] = 0.f; acc1[b] = 0.f; }
    for (int k4 = 0; k4 < 128; ++k4) {
        const int k = k4 * 4;
        float w0[4], w1[4];
#pragma unroll
        for (int i = 0; i < 4; ++i) {
            w0[i] = Wih[(size_t)(k + i) * G4 + j];
            w1[i] = Wih[(size_t)(k + i) * G4 + j + 256];
        }
#pragma unroll
        for (int b = 0; b < BB; ++b) {
            const float4 xv = *reinterpret_cast<const float4*>(x + b * 512 + k);
            acc0[b] += xv.x * w0[0] + xv.y * w0[1] + xv.z * w0[2] + xv.w * w0[3];
            acc1[b] += xv.x * w1[0] + xv.y * w1[1] + xv.z * w1[2] + xv.w * w1[3];
        }
    }
#pragma unroll
    for (int b = 0; b < BB; ++b) {
        g_E[(size_t)(v0 + b) * G4 + j]       = acc0[b];
        g_E[(size_t)(v0 + b) * G4 + j + 256] = acc1[b];
    }
}

// ---------------- K2: initial LSTM step (tok=BLANK, h=c=0) ----------------
__global__ void k_init(const float* __restrict__ bl) {
    const int k = threadIdx.x;  // 512
    const float ig = g_E[k]        + bl[k];
    const float gg = g_E[1024 + k] + bl[1024 + k];
    const float og = g_E[1536 + k] + bl[1536 + k];
    const float si = 1.f / (1.f + expf(-ig));
    const float so = 1.f / (1.f + expf(-og));
    const float c1 = si * tanhf(gg);        // sig(f)*c0 = 0
    const float h1 = so * tanhf(c1);
    for (int b = 0; b < BB; ++b) {
        g_outPN[k * BB + b] = h1;
        g_h[k * BB + b]     = h1;
        g_c[b * HH + k]     = c1;
    }
    if (k < BB) g_score[k] = 0.f;
}

// matvec over K=512 with LDS-resident 16-column weight slice; writes k-split partials.
__device__ __forceinline__ void matvec_part(const float* __restrict__ xsrc,
                                            const float* w_lds, float* part,
                                            int wv_, int cp, int rq) {
    float a00 = 0, a01 = 0, a02 = 0, a03 = 0, a10 = 0, a11 = 0, a12 = 0, a13 = 0;
    const int kbase = wv_ << 6;
#pragma unroll 4
    for (int ki = 0; ki < 64; ++ki) {
        const int k = kbase + ki;
        const float4 xv = *reinterpret_cast<const float4*>(xsrc + k * BB + rq * 4);
        const float2 wv = *reinterpret_cast<const float2*>(w_lds + k * 16 + cp * 2);
        a00 += wv.x * xv.x; a01 += wv.x * xv.y; a02 += wv.x * xv.z; a03 += wv.x * xv.w;
        a10 += wv.y * xv.x; a11 += wv.y * xv.y; a12 += wv.y * xv.z; a13 += wv.y * xv.w;
    }
    float* p = part + wv_ * 520 + (cp * 2) * 32 + rq * 4;
    p[0] = a00; p[1] = a01; p[2] = a02; p[3] = a03;
    p += 32;
    p[0] = a10; p[1] = a11; p[2] = a12; p[3] = a13;
}

// ---------------- K3: persistent cooperative scan ----------------
// roles: [0,32) W_dec (joint) | [32,96) W_out (logits) | [96,224) W_hh | [224,256) per-row LSTM
__global__ __launch_bounds__(512) void k_loop(const float* __restrict__ Wdec,
                                              const float* __restrict__ Wout,
                                              const float* __restrict__ Whh,
                                              const float* __restrict__ bj,
                                              const float* __restrict__ bl,
                                              float* __restrict__ out) {
    cg::grid_group gridg = cg::this_grid();
    __shared__ __align__(16) float w_lds[512 * 16];   // 32 KB
    __shared__ __align__(16) float part[8 * 520];     // 16.6 KB
    __shared__ int ls_pos;

    const int blk = blockIdx.x;
    const int tid = threadIdx.x;
    int role, ord;
    if (blk < 32)       { role = 0; ord = blk; }
    else if (blk < 96)  { role = 1; ord = blk - 32; }
    else if (blk < 224) { role = 2; ord = blk - 96; }
    else                { role = 3; ord = blk - 224; }

    if (role <= 2) {
        const float* W = (role == 0) ? Wdec : (role == 1) ? Wout : Whh;
        const int ldw  = (role == 0) ? JJ   : (role == 1) ? VV   : G4;
        const int cb = ord * 16;
        const int c = tid & 15, k0 = tid >> 4;
        for (int k = k0; k < 512; k += 32)
            w_lds[k * 16 + c] = W[(size_t)k * ldw + cb + c];
    }
    const int jj = tid >> 5;    // 0..15 (local col for reduce/epilogue)
    const int bb = tid & 31;    // batch row
    const int wv_ = tid >> 6;   // wave = k-chunk
    const int lane = tid & 63;
    const int cp = lane & 7;    // col pair
    const int rq = lane >> 3;   // row quad
    float bj_reg = 0.f;
    if (role == 0) bj_reg = bj[ord * 16 + jj];
    __syncthreads();

    for (int t = 0; t < TT; ++t) {
        // ---- phase 1: joint = tanh(enc + out_PN@W_dec + bj); hW = h@W_hh
        if (role == 0 || role == 2) {
            matvec_part((role == 0) ? g_outPN : g_h, w_lds, part, wv_, cp, rq);
            __syncthreads();
            float s = 0.f;
#pragma unroll
            for (int w = 0; w < 8; ++w) s += part[w * 520 + jj * 32 + bb];
            const int col = ord * 16 + jj;
            if (role == 0) {
                const float u = s + g_encp[(size_t)t * JJ * BB + col * BB + bb] + bj_reg;
                g_joint[col * BB + bb] = tanhf(u);
            } else {
                g_hW[bb * G4 + col] = s;
            }
        }
        gridg.sync();
        // ---- phase 2: logits = joint@W_out; per-block (max, argmax, sumexp) partials
        if (role == 1) {
            matvec_part(g_joint, w_lds, part, wv_, cp, rq);
            __syncthreads();
            float s = 0.f;
#pragma unroll
            for (int w = 0; w < 8; ++w) s += part[w * 520 + jj * 32 + bb];
            __syncthreads();
            part[jj * 32 + bb] = s;   // stash logits [jj][b]
            __syncthreads();
            if (tid < 32) {
                const int b = tid;
                float m = -INFINITY; int p = 0;
#pragma unroll
                for (int q = 0; q < 16; ++q) {
                    const float l = part[q * 32 + b];
                    if (l > m) { m = l; p = ord * 16 + q; }
                }
                float s2 = 0.f;
#pragma unroll
                for (int q = 0; q < 16; ++q) s2 += expf(part[q * 32 + b] - m);
                g_pmax[b * 64 + ord] = m;
                g_psum[b * 64 + ord] = s2;
                g_parg[b * 64 + ord] = p;
            }
        }
        gridg.sync();
        // ---- phase 3: reduce partials -> pos/lp; LSTM cell + conditional state update
        if (role == 3) {
            const int b = ord;
            if (tid < 64) {
                float m = g_pmax[b * 64 + tid];
                const float s2 = g_psum[b * 64 + tid];
                int p = g_parg[b * 64 + tid];
                const float m0 = m;
#pragma unroll
                for (int off = 32; off; off >>= 1) {
                    const float om = __shfl_xor(m, off, 64);
                    const int   op = __shfl_xor(p, off, 64);
                    if (om > m || (om == m && op < p)) { m = om; p = op; }
                }
                float val = s2 * expf(m0 - m);
#pragma unroll
                for (int off = 32; off; off >>= 1) val += __shfl_xor(val, off, 64);
                if (tid == 0) {
                    ls_pos = p;
                    out[b * TT + t] = (float)p;             // tok == pos (BLANK=0 case coincides)
                    if (p != 0) g_score[b] += -logf(val);   // lp = -log(sum exp(l - max))
                }
            }
            __syncthreads();
            const int pos = ls_pos;
            const bool emit = (pos != 0);
            const int k = tid;
            const float* Ep  = g_E + (size_t)pos * G4;
            const float* hWp = g_hW + b * G4;
            const float ig = Ep[k]        + hWp[k]        + bl[k];
            const float fg = Ep[512 + k]  + hWp[512 + k]  + bl[512 + k];
            const float gg = Ep[1024 + k] + hWp[1024 + k] + bl[1024 + k];
            const float og = Ep[1536 + k] + hWp[1536 + k] + bl[1536 + k];
            const float si = 1.f / (1.f + expf(-ig));
            const float sf = 1.f / (1.f + expf(-fg));
            const float so = 1.f / (1.f + expf(-og));
            const float cn = sf * g_c[b * HH + k] + si * tanhf(gg);
            const float hn = so * tanhf(cn);
            if (emit) {
                g_c[b * HH + k]     = cn;
                g_h[k * BB + b]     = hn;
                g_outPN[k * BB + b] = hn;
            }
        }
        gridg.sync();
    }
}

// ---------------- K4: scores + mean(exp(score)) ----------------
__global__ void k_final(float* __restrict__ out) {
    const int b = threadIdx.x;  // 64 threads
    float e = 0.f;
    if (b < BB) {
        const float sc = g_score[b];
        out[BB * TT + b] = sc;
        e = expf(sc);
    }
#pragma unroll
    for (int off = 32; off; off >>= 1) e += __shfl_xor(e, off, 64);
    if (b == 0) out[BB * TT + BB] = e / (float)BB;
}

extern "C" void kernel_launch(void* const* d_in, const int* in_sizes, int n_in,
                              void* d_out, int out_size, void* d_ws, size_t ws_size,
                              hipStream_t stream) {
    const float* enc  = (const float*)d_in[0];
    const float* emb  = (const float*)d_in[1];
    const float* Wih  = (const float*)d_in[2];
    const float* Whh  = (const float*)d_in[3];
    const float* bl   = (const float*)d_in[4];
    const float* Wenc = (const float*)d_in[5];
    const float* Wdec = (const float*)d_in[6];
    const float* bj   = (const float*)d_in[7];
    const float* Wout = (const float*)d_in[8];
    float* out = (float*)d_out;

    hipLaunchKernelGGL(k_encproj, dim3(TT), dim3(256), 0, stream, enc, Wenc);
    hipLaunchKernelGGL(k_embproj, dim3(128), dim3(256), 0, stream, emb, Wih);
    hipLaunchKernelGGL(k_init, dim3(1), dim3(512), 0, stream, bl);

    void* args[] = { (void*)&Wdec, (void*)&Wout, (void*)&Whh,
                     (void*)&bj, (void*)&bl, (void*)&out };
    hipLaunchCooperativeKernel((const void*)k_loop, dim3(256), dim3(512), args, 0, stream);

    hipLaunchKernelGGL(k_final, dim3(1), dim3(64), 0, stream, out);
}

// Round 2
// 32600.662 us; speedup vs baseline: 3.0357x; 3.0357x over previous
//
#include <hip/hip_runtime.h>
#include <math.h>

#define BB 32
#define TT 1000
#define HH 512
#define JJ 512
#define VV 1024
#define G4 2048
#define NB 128
#define NT 1024
#define GRPS 8

// ---- persistent device-side scratch ----
__device__ __align__(16) float g_encp[(size_t)TT * JJ * BB];  // [t][j][b]
__device__ __align__(16) float g_E[(size_t)VV * G4];          // [v][g] = embed @ W_ih
__device__ __align__(16) float g_h[HH * BB];                  // [k][b]  (== out_PN)
__device__ __align__(16) float g_c[BB * HH];                  // [b][k]
__device__ __align__(16) float g_joint[JJ * BB];              // [j][b]
__device__ __align__(16) float g_hW[G4 * BB];                 // [g][b]
__device__ __align__(16) float g_logits[VV * BB];             // [v][b]
__device__ float g_score[BB];
// barrier state (reset by k_init each launch)
__device__ int g_bcnt[GRPS * 32];
__device__ int g_btop;
__device__ int g_bgen[GRPS * 32];

// ---------------- custom two-level grid barrier ----------------
__device__ __forceinline__ void gbar(int grp, int target) {
    __syncthreads();
    if (threadIdx.x == 0) {
        // release: push this block's writes to the device coherence point
        __builtin_amdgcn_fence(__ATOMIC_RELEASE, "agent");
        int p = __hip_atomic_fetch_add(&g_bcnt[grp * 32], 1, __ATOMIC_RELAXED,
                                       __HIP_MEMORY_SCOPE_AGENT);
        if (p == (NB / GRPS) - 1) {          // last block of my group
            __hip_atomic_store(&g_bcnt[grp * 32], 0, __ATOMIC_RELAXED,
                               __HIP_MEMORY_SCOPE_AGENT);
            __builtin_amdgcn_fence(__ATOMIC_RELEASE, "agent");   // order reset before top-arrive
            int q = __hip_atomic_fetch_add(&g_btop, 1, __ATOMIC_RELAXED,
                                           __HIP_MEMORY_SCOPE_AGENT);
            if (q == GRPS - 1) {             // last group: publish
                __hip_atomic_store(&g_btop, 0, __ATOMIC_RELAXED,
                                   __HIP_MEMORY_SCOPE_AGENT);
                __builtin_amdgcn_fence(__ATOMIC_RELEASE, "agent"); // order resets before flags
                for (int i = 0; i < GRPS; ++i)
                    __hip_atomic_store(&g_bgen[i * 32], target, __ATOMIC_RELAXED,
                                       __HIP_MEMORY_SCOPE_AGENT);
            }
        }
        while (__hip_atomic_load(&g_bgen[grp * 32], __ATOMIC_RELAXED,
                                 __HIP_MEMORY_SCOPE_AGENT) < target)
            __builtin_amdgcn_s_sleep(1);
        // acquire: invalidate local caches so we observe everything published
        __builtin_amdgcn_fence(__ATOMIC_ACQUIRE, "agent");
    }
    __syncthreads();
}

// ---------------- K0: enc_proj[t][j][b] ----------------
__global__ __launch_bounds__(256) void k_encproj(const float* __restrict__ enc,
                                                 const float* __restrict__ Wenc) {
    __shared__ __align__(16) float x[BB * 512];
    const int t = blockIdx.x;
    for (int i = threadIdx.x; i < BB * 128; i += 256) {
        const int b = i >> 7, k4 = i & 127;
        *reinterpret_cast<float4*>(x + b * 512 + k4 * 4) =
            *reinterpret_cast<const float4*>(enc + ((size_t)(b * TT + t)) * 512 + k4 * 4);
    }
    __syncthreads();
    const int j = threadIdx.x;
    float acc0[BB], acc1[BB];
#pragma unroll
    for (int b = 0; b < BB; ++b) { acc0[b] = 0.f; acc1[b] = 0.f; }
    for (int k4 = 0; k4 < 128; ++k4) {
        const int k = k4 * 4;
        float w0[4], w1[4];
#pragma unroll
        for (int i = 0; i < 4; ++i) {
            w0[i] = Wenc[(size_t)(k + i) * JJ + j];
            w1[i] = Wenc[(size_t)(k + i) * JJ + j + 256];
        }
#pragma unroll
        for (int b = 0; b < BB; ++b) {
            const float4 xv = *reinterpret_cast<const float4*>(x + b * 512 + k);
            acc0[b] += xv.x * w0[0] + xv.y * w0[1] + xv.z * w0[2] + xv.w * w0[3];
            acc1[b] += xv.x * w1[0] + xv.y * w1[1] + xv.z * w1[2] + xv.w * w1[3];
        }
    }
    float* outt = g_encp + (size_t)t * JJ * BB;
#pragma unroll
    for (int b = 0; b < BB; ++b) {
        outt[j * BB + b]         = acc0[b];
        outt[(j + 256) * BB + b] = acc1[b];
    }
}

// ---------------- K1: E = embed @ W_ih ----------------
__global__ __launch_bounds__(256) void k_embproj(const float* __restrict__ emb,
                                                 const float* __restrict__ Wih) {
    __shared__ __align__(16) float x[BB * 512];
    const int v0 = (blockIdx.x >> 2) * 32;
    const int g0 = (blockIdx.x & 3) * 512;
    for (int i = threadIdx.x; i < BB * 128; i += 256) {
        const int b = i >> 7, k4 = i & 127;
        *reinterpret_cast<float4*>(x + b * 512 + k4 * 4) =
            *reinterpret_cast<const float4*>(emb + (size_t)(v0 + b) * 512 + k4 * 4);
    }
    __syncthreads();
    const int j = g0 + threadIdx.x;
    float acc0[BB], acc1[BB];
#pragma unroll
    for (int b = 0; b < BB; ++b) { acc0[b] = 0.f; acc1[b] = 0.f; }
    for (int k4 = 0; k4 < 128; ++k4) {
        const int k = k4 * 4;
        float w0[4], w1[4];
#pragma unroll
        for (int i = 0; i < 4; ++i) {
            w0[i] = Wih[(size_t)(k + i) * G4 + j];
            w1[i] = Wih[(size_t)(k + i) * G4 + j + 256];
        }
#pragma unroll
        for (int b = 0; b < BB; ++b) {
            const float4 xv = *reinterpret_cast<const float4*>(x + b * 512 + k);
            acc0[b] += xv.x * w0[0] + xv.y * w0[1] + xv.z * w0[2] + xv.w * w0[3];
            acc1[b] += xv.x * w1[0] + xv.y * w1[1] + xv.z * w1[2] + xv.w * w1[3];
        }
    }
#pragma unroll
    for (int b = 0; b < BB; ++b) {
        g_E[(size_t)(v0 + b) * G4 + j]       = acc0[b];
        g_E[(size_t)(v0 + b) * G4 + j + 256] = acc1[b];
    }
}

// ---------------- K2: initial LSTM step + barrier reset ----------------
__global__ void k_init(const float* __restrict__ bl) {
    const int k = threadIdx.x;  // 512
    const float ig = g_E[k]        + bl[k];
    const float gg = g_E[1024 + k] + bl[1024 + k];
    const float og = g_E[1536 + k] + bl[1536 + k];
    const float si = 1.f / (1.f + expf(-ig));
    const float so = 1.f / (1.f + expf(-og));
    const float c1 = si * tanhf(gg);
    const float h1 = so * tanhf(c1);
    for (int b = 0; b < BB; ++b) {
        g_h[k * BB + b] = h1;
        g_c[b * HH + k] = c1;
    }
    if (k < BB) g_score[k] = 0.f;
    if (k < GRPS) { g_bcnt[k * 32] = 0; g_bgen[k * 32] = 0; }
    if (k == 0) g_btop = 0;
}

// register-tiled 4cols x 32rows matvec over K=512; lane = (ks: k-seg, b4: b-quad)
__device__ __forceinline__ void mv_tile(const float* __restrict__ wl, const int ldw,
                                        const int c0, const float* __restrict__ x,
                                        const int ks, const int b4, float acc[4][4]) {
#pragma unroll
    for (int c = 0; c < 4; ++c)
#pragma unroll
        for (int r = 0; r < 4; ++r) acc[c][r] = 0.f;
#pragma unroll 4
    for (int i = 0; i < 64; ++i) {
        const int k = ks * 64 + i;
        const float4 xv = *reinterpret_cast<const float4*>(x + k * BB + b4 * 4);
        const float4 wv = *reinterpret_cast<const float4*>(wl + k * ldw + c0);
        acc[0][0] += wv.x * xv.x; acc[0][1] += wv.x * xv.y; acc[0][2] += wv.x * xv.z; acc[0][3] += wv.x * xv.w;
        acc[1][0] += wv.y * xv.x; acc[1][1] += wv.y * xv.y; acc[1][2] += wv.y * xv.z; acc[1][3] += wv.y * xv.w;
        acc[2][0] += wv.z * xv.x; acc[2][1] += wv.z * xv.y; acc[2][2] += wv.z * xv.z; acc[2][3] += wv.z * xv.w;
        acc[3][0] += wv.w * xv.x; acc[3][1] += wv.w * xv.y; acc[3][2] += wv.w * xv.z; acc[3][3] += wv.w * xv.w;
    }
    // reduce across the 8 k-segments (lane bits 3..5)
#pragma unroll
    for (int off = 8; off <= 32; off <<= 1)
#pragma unroll
        for (int c = 0; c < 4; ++c)
#pragma unroll
            for (int r = 0; r < 4; ++r) acc[c][r] += __shfl_xor(acc[c][r], off, 64);
}

// ---------------- K3: persistent scan, custom barriers ----------------
__global__ __launch_bounds__(NT) void k_loop(const float* __restrict__ Wdec,
                                             const float* __restrict__ Wout,
                                             const float* __restrict__ Whh,
                                             const float* __restrict__ bj,
                                             const float* __restrict__ bl,
                                             float* __restrict__ out) {
    __shared__ __align__(16) float wd_lds[512 * 4];    //  8 KB
    __shared__ __align__(16) float whh_lds[512 * 16];  // 32 KB
    __shared__ __align__(16) float wout_lds[512 * 8];  // 16 KB
    __shared__ __align__(16) float h_lds[512 * BB];    // 64 KB
    __shared__ float red_f[32];
    __shared__ int   red_i[32];
    __shared__ int   ls_pos;
    __shared__ float ls_m;

    const int blk  = blockIdx.x;
    const int grp  = blk & (GRPS - 1);
    const int tid  = threadIdx.x;
    const int wv   = tid >> 6;
    const int lane = tid & 63;
    const int ks   = lane >> 3;   // k-segment 0..7
    const int b4   = lane & 7;    // b-quad    0..7

    // preload weight slices into LDS (once)
    for (int i = tid; i < 512 * 4; i += NT) {
        const int k = i >> 2, c = i & 3;
        wd_lds[i] = Wdec[(size_t)k * JJ + blk * 4 + c];
    }
    for (int i = tid; i < 512 * 16; i += NT) {
        const int k = i >> 4, c = i & 15;
        whh_lds[i] = Whh[(size_t)k * G4 + blk * 16 + c];
    }
    for (int i = tid; i < 512 * 8; i += NT) {
        const int k = i >> 3, c = i & 7;
        wout_lds[i] = Wout[(size_t)k * VV + blk * 8 + c];
    }
    float bjr[4];
#pragma unroll
    for (int c = 0; c < 4; ++c) bjr[c] = bj[blk * 4 + c];

    int bt = 0;
    float acc[4][4];
    for (int t = 0; t < TT; ++t) {
        // ---- window A: stage h; wave0 computes joint for this block's 4 W_dec cols
        {
            const float4* gh4 = reinterpret_cast<const float4*>(g_h);
            float4* hl4 = reinterpret_cast<float4*>(h_lds);
#pragma unroll
            for (int p = 0; p < 4; ++p) hl4[tid + p * NT] = gh4[tid + p * NT];
        }
        __syncthreads();
        if (wv == 0) {
            mv_tile(wd_lds, 4, 0, h_lds, ks, b4, acc);
            if (ks == 0) {
                const float* ep = g_encp + (size_t)t * JJ * BB;
#pragma unroll
                for (int c = 0; c < 4; ++c) {
                    const int col = blk * 4 + c;
                    const float4 ev = *reinterpret_cast<const float4*>(ep + col * BB + b4 * 4);
                    float4 jv;
                    jv.x = tanhf(acc[c][0] + ev.x + bjr[c]);
                    jv.y = tanhf(acc[c][1] + ev.y + bjr[c]);
                    jv.z = tanhf(acc[c][2] + ev.z + bjr[c]);
                    jv.w = tanhf(acc[c][3] + ev.w + bjr[c]);
                    *reinterpret_cast<float4*>(g_joint + col * BB + b4 * 4) = jv;
                }
            }
        }
        gbar(grp, ++bt);

        // ---- window B: hW = h@W_hh (waves 0..3), logits = joint@W_out (waves 4..5)
        if (wv < 4) {
            mv_tile(whh_lds, 16, wv * 4, h_lds, ks, b4, acc);
            if (ks == 0) {
#pragma unroll
                for (int c = 0; c < 4; ++c) {
                    const int col = blk * 16 + wv * 4 + c;
                    float4 v = { acc[c][0], acc[c][1], acc[c][2], acc[c][3] };
                    *reinterpret_cast<float4*>(g_hW + (size_t)col * BB + b4 * 4) = v;
                }
            }
        } else if (wv < 6) {
            mv_tile(wout_lds, 8, (wv - 4) * 4, g_joint, ks, b4, acc);
            if (ks == 0) {
#pragma unroll
                for (int c = 0; c < 4; ++c) {
                    const int col = blk * 8 + (wv - 4) * 4 + c;
                    float4 v = { acc[c][0], acc[c][1], acc[c][2], acc[c][3] };
                    *reinterpret_cast<float4*>(g_logits + (size_t)col * BB + b4 * 4) = v;
                }
            }
        }
        gbar(grp, ++bt);

        // ---- window C: blocks 0..31 do argmax + log-softmax + LSTM for row blk
        if (blk < BB) {
            const int r = blk;
            const float l = g_logits[(size_t)tid * BB + r];
            float m = l; int pi = tid;
#pragma unroll
            for (int off = 32; off; off >>= 1) {
                const float om = __shfl_xor(m, off, 64);
                const int   op = __shfl_xor(pi, off, 64);
                if (om > m || (om == m && op < pi)) { m = om; pi = op; }
            }
            if (lane == 0) { red_f[wv] = m; red_i[wv] = pi; }
            __syncthreads();
            if (wv == 0) {
                float m2 = (lane < 16) ? red_f[lane] : -INFINITY;
                int   p2 = (lane < 16) ? red_i[lane] : (1 << 30);
#pragma unroll
                for (int off = 8; off; off >>= 1) {
                    const float om = __shfl_xor(m2, off, 64);
                    const int   op = __shfl_xor(p2, off, 64);
                    if (om > m2 || (om == m2 && op < p2)) { m2 = om; p2 = op; }
                }
                if (lane == 0) { ls_pos = p2; ls_m = m2; }
            }
            __syncthreads();
            const int pos = ls_pos;
            const float mx = ls_m;
            float se = expf(l - mx);
#pragma unroll
            for (int off = 32; off; off >>= 1) se += __shfl_xor(se, off, 64);
            if (lane == 0) red_f[wv] = se;
            __syncthreads();
            if (wv == 0) {
                float s2 = (lane < 16) ? red_f[lane] : 0.f;
#pragma unroll
                for (int off = 8; off; off >>= 1) s2 += __shfl_xor(s2, off, 64);
                if (lane == 0) {
                    out[r * TT + t] = (float)pos;
                    if (pos != 0) g_score[r] += -logf(s2);
                }
            }
            // LSTM cell + conditional state update
            if (tid < HH && pos != 0) {
                const int k = tid;
                const float* Ep = g_E + (size_t)pos * G4;
                const float i_g = Ep[k]        + g_hW[(size_t)k * BB + r]          + bl[k];
                const float f_g = Ep[512 + k]  + g_hW[(size_t)(512 + k) * BB + r]  + bl[512 + k];
                const float g_g = Ep[1024 + k] + g_hW[(size_t)(1024 + k) * BB + r] + bl[1024 + k];
                const float o_g = Ep[1536 + k] + g_hW[(size_t)(1536 + k) * BB + r] + bl[1536 + k];
                const float si = 1.f / (1.f + expf(-i_g));
                const float sf = 1.f / (1.f + expf(-f_g));
                const float so = 1.f / (1.f + expf(-o_g));
                const float cn = sf * g_c[r * HH + k] + si * tanhf(g_g);
                const float hn = so * tanhf(cn);
                g_c[r * HH + k] = cn;
                g_h[k * BB + r] = hn;
            }
        }
        gbar(grp, ++bt);
    }
}

// ---------------- K4: scores + mean(exp(score)) ----------------
__global__ void k_final(float* __restrict__ out) {
    const int b = threadIdx.x;  // 64 threads
    float e = 0.f;
    if (b < BB) {
        const float sc = g_score[b];
        out[BB * TT + b] = sc;
        e = expf(sc);
    }
#pragma unroll
    for (int off = 32; off; off >>= 1) e += __shfl_xor(e, off, 64);
    if (b == 0) out[BB * TT + BB] = e / (float)BB;
}

extern "C" void kernel_launch(void* const* d_in, const int* in_sizes, int n_in,
                              void* d_out, int out_size, void* d_ws, size_t ws_size,
                              hipStream_t stream) {
    const float* enc  = (const float*)d_in[0];
    const float* emb  = (const float*)d_in[1];
    const float* Wih  = (const float*)d_in[2];
    const float* Whh  = (const float*)d_in[3];
    const float* bl   = (const float*)d_in[4];
    const float* Wenc = (const float*)d_in[5];
    const float* Wdec = (const float*)d_in[6];
    const float* bj   = (const float*)d_in[7];
    const float* Wout = (const float*)d_in[8];
    float* out = (float*)d_out;

    hipLaunchKernelGGL(k_encproj, dim3(TT), dim3(256), 0, stream, enc, Wenc);
    hipLaunchKernelGGL(k_embproj, dim3(128), dim3(256), 0, stream, emb, Wih);
    hipLaunchKernelGGL(k_init, dim3(1), dim3(512), 0, stream, bl);

    void* args[] = { (void*)&Wdec, (void*)&Wout, (void*)&Whh,
                     (void*)&bj, (void*)&bl, (void*)&out };
    hipLaunchCooperativeKernel((const void*)k_loop, dim3(NB), dim3(NT), args, 0, stream);

    hipLaunchKernelGGL(k_final, dim3(1), dim3(64), 0, stream, out);
}

// Round 4
// 28166.461 us; speedup vs baseline: 3.5136x; 1.1574x over previous
//
#include <hip/hip_runtime.h>
#include <math.h>

#define BB 32
#define TT 1000
#define HH 512
#define JJ 512
#define VV 1024
#define G4 2048
#define NB 128
#define NT 1024
#define NGRP 16
#define BPG (NB / NGRP)

#define RLX __ATOMIC_RELAXED
#define AGT __HIP_MEMORY_SCOPE_AGENT

// ---- persistent device-side scratch ----
__device__ __align__(16) float g_encp[(size_t)TT * JJ * BB];  // [t][j][b]
__device__ __align__(16) float g_E[(size_t)VV * G4];          // [v][g]
__device__ __align__(16) float g_h[HH * BB];                  // [k][b] (== out_PN)
__device__ __align__(16) float g_c[BB * HH];                  // [b][k]
__device__ __align__(16) float g_joint[JJ * BB];              // [j][b]
__device__ __align__(16) float g_hW[BB * G4];                 // [b][g]
__device__ float g_pm[BB * NB];                               // [b][blk] partial max
__device__ float g_ps[BB * NB];                               // [b][blk] partial sumexp
__device__ int   g_pa[BB * NB];                               // [b][blk] partial argmax
__device__ float g_score[BB];
// fence-free barrier state: monotonic counters, per phase (0=A,1=B,2=C)
__device__ int g_cnt[3 * 1024];   // [ph][grp*64]
__device__ int g_top[3 * 64];     // [ph*64]
__device__ int g_gen[3 * 1024];   // [ph][grp*64]

// ---------------- fence-free two-level barrier ----------------
__device__ __forceinline__ void gbar_arrive(int grp, int ph, int tp1) {
    __syncthreads();   // per-wave vmcnt drain before s_barrier -> block's stores visible
    if (threadIdx.x == 0) {
        int p = __hip_atomic_fetch_add(&g_cnt[ph * 1024 + grp * 64], 1, RLX, AGT);
        if (p == tp1 * BPG - 1) {                       // my group complete for barrier tp1
            int q = __hip_atomic_fetch_add(&g_top[ph * 64], 1, RLX, AGT);
            if (q == tp1 * NGRP - 1) {                  // all groups complete: publish
#pragma unroll
                for (int i = 0; i < NGRP; ++i)
                    __hip_atomic_store(&g_gen[ph * 1024 + i * 64], tp1, RLX, AGT);
            }
        }
    }
}
__device__ __forceinline__ void gbar_wait(int grp, int ph, int tp1) {
    if (threadIdx.x == 0) {
        while (__hip_atomic_load(&g_gen[ph * 1024 + grp * 64], RLX, AGT) < tp1)
            __builtin_amdgcn_s_sleep(1);
    }
    __syncthreads();
}

// ---------------- K0: enc_proj[t][j][b] ----------------
__global__ __launch_bounds__(256) void k_encproj(const float* __restrict__ enc,
                                                 const float* __restrict__ Wenc) {
    __shared__ __align__(16) float x[BB * 512];
    const int t = blockIdx.x;
    for (int i = threadIdx.x; i < BB * 128; i += 256) {
        const int b = i >> 7, k4 = i & 127;
        *reinterpret_cast<float4*>(x + b * 512 + k4 * 4) =
            *reinterpret_cast<const float4*>(enc + ((size_t)(b * TT + t)) * 512 + k4 * 4);
    }
    __syncthreads();
    const int j = threadIdx.x;
    float acc0[BB], acc1[BB];
#pragma unroll
    for (int b = 0; b < BB; ++b) { acc0[b] = 0.f; acc1[b] = 0.f; }
    for (int k4 = 0; k4 < 128; ++k4) {
        const int k = k4 * 4;
        float w0[4], w1[4];
#pragma unroll
        for (int i = 0; i < 4; ++i) {
            w0[i] = Wenc[(size_t)(k + i) * JJ + j];
            w1[i] = Wenc[(size_t)(k + i) * JJ + j + 256];
        }
#pragma unroll
        for (int b = 0; b < BB; ++b) {
            const float4 xv = *reinterpret_cast<const float4*>(x + b * 512 + k);
            acc0[b] += xv.x * w0[0] + xv.y * w0[1] + xv.z * w0[2] + xv.w * w0[3];
            acc1[b] += xv.x * w1[0] + xv.y * w1[1] + xv.z * w1[2] + xv.w * w1[3];
        }
    }
    float* outt = g_encp + (size_t)t * JJ * BB;
#pragma unroll
    for (int b = 0; b < BB; ++b) {
        outt[j * BB + b]         = acc0[b];
        outt[(j + 256) * BB + b] = acc1[b];
    }
}

// ---------------- K1: E = embed @ W_ih ----------------
__global__ __launch_bounds__(256) void k_embproj(const float* __restrict__ emb,
                                                 const float* __restrict__ Wih) {
    __shared__ __align__(16) float x[BB * 512];
    const int v0 = (blockIdx.x >> 2) * 32;
    const int g0 = (blockIdx.x & 3) * 512;
    for (int i = threadIdx.x; i < BB * 128; i += 256) {
        const int b = i >> 7, k4 = i & 127;
        *reinterpret_cast<float4*>(x + b * 512 + k4 * 4) =
            *reinterpret_cast<const float4*>(emb + (size_t)(v0 + b) * 512 + k4 * 4);
    }
    __syncthreads();
    const int j = g0 + threadIdx.x;
    float acc0[BB], acc1[BB];
#pragma unroll
    for (int b = 0; b < BB; ++b) { acc0[b] = 0.f; acc1[b] = 0.f; }
    for (int k4 = 0; k4 < 128; ++k4) {
        const int k = k4 * 4;
        float w0[4], w1[4];
#pragma unroll
        for (int i = 0; i < 4; ++i) {
            w0[i] = Wih[(size_t)(k + i) * G4 + j];
            w1[i] = Wih[(size_t)(k + i) * G4 + j + 256];
        }
#pragma unroll
        for (int b = 0; b < BB; ++b) {
            const float4 xv = *reinterpret_cast<const float4*>(x + b * 512 + k);
            acc0[b] += xv.x * w0[0] + xv.y * w0[1] + xv.z * w0[2] + xv.w * w0[3];
            acc1[b] += xv.x * w1[0] + xv.y * w1[1] + xv.z * w1[2] + xv.w * w1[3];
        }
    }
#pragma unroll
    for (int b = 0; b < BB; ++b) {
        g_E[(size_t)(v0 + b) * G4 + j]       = acc0[b];
        g_E[(size_t)(v0 + b) * G4 + j + 256] = acc1[b];
    }
}

// ---------------- K2: initial LSTM step + state/barrier reset ----------------
__global__ void k_init(const float* __restrict__ bl) {
    const int k = threadIdx.x;  // 512
    const float ig = g_E[k]        + bl[k];
    const float gg = g_E[1024 + k] + bl[1024 + k];
    const float og = g_E[1536 + k] + bl[1536 + k];
    const float si = 1.f / (1.f + expf(-ig));
    const float so = 1.f / (1.f + expf(-og));
    const float c1 = si * tanhf(gg);
    const float h1 = so * tanhf(c1);
    for (int b = 0; b < BB; ++b) {
        g_h[k * BB + b] = h1;
        g_c[b * HH + k] = c1;
    }
    if (k < BB) g_score[k] = 0.f;
    for (int i = k; i < 3 * 1024; i += 512) { g_cnt[i] = 0; g_gen[i] = 0; }
    if (k < 3 * 64) g_top[k] = 0;
}

// 4-col x 32-b tile, K covered by ks-interleaved slices (k = k0 + i*8 + ks).
// w rows padded to `wpad` floats -> the 8 ks-lane float4 reads tile all 32 banks.
// Butterfly over ks bits leaves totals in ALL lanes.
template<int KN>
__device__ __forceinline__ void mv4(const float* __restrict__ w_lds, const int wpad,
                                    const int c0, const int k0,
                                    const float* __restrict__ x_lds,
                                    const int ks, const int b4, float acc[4][4]) {
#pragma unroll
    for (int c = 0; c < 4; ++c)
#pragma unroll
        for (int r = 0; r < 4; ++r) acc[c][r] = 0.f;
#pragma unroll 8
    for (int i = 0; i < KN; ++i) {
        const int k = k0 + i * 8 + ks;
        const float4 xv = *reinterpret_cast<const float4*>(x_lds + k * 32 + b4 * 4);
        const float4 wv = *reinterpret_cast<const float4*>(w_lds + k * wpad + c0);
        acc[0][0] += wv.x * xv.x; acc[0][1] += wv.x * xv.y; acc[0][2] += wv.x * xv.z; acc[0][3] += wv.x * xv.w;
        acc[1][0] += wv.y * xv.x; acc[1][1] += wv.y * xv.y; acc[1][2] += wv.y * xv.z; acc[1][3] += wv.y * xv.w;
        acc[2][0] += wv.z * xv.x; acc[2][1] += wv.z * xv.y; acc[2][2] += wv.z * xv.z; acc[2][3] += wv.z * xv.w;
        acc[3][0] += wv.w * xv.x; acc[3][1] += wv.w * xv.y; acc[3][2] += wv.w * xv.z; acc[3][3] += wv.w * xv.w;
    }
#pragma unroll
    for (int off = 8; off <= 32; off <<= 1)
#pragma unroll
        for (int c = 0; c < 4; ++c)
#pragma unroll
            for (int r = 0; r < 4; ++r) acc[c][r] += __shfl_xor(acc[c][r], off, 64);
}

// ---------------- K3: persistent scan, fence-free barriers ----------------
__global__ __launch_bounds__(NT) void k_loop(const float* __restrict__ Wdec,
                                             const float* __restrict__ Wout,
                                             const float* __restrict__ Whh,
                                             const float* __restrict__ bj,
                                             const float* __restrict__ bl,
                                             float* __restrict__ out) {
    __shared__ __align__(16) float x_lds[512 * 32];     // 64 KB: h, then joint
    __shared__ __align__(16) float wab_lds[512 * 20];   // 40 KB: cols 0-15 Whh, 16-19 Wdec
    __shared__ __align__(16) float wout_lds[512 * 12];  // 24 KB: cols 0-7 Wout
    __shared__ float part_lds[2 * 160];
    __shared__ float logit_lds[8 * 33];
    __shared__ float red_m[2], red_s[2];
    __shared__ int   red_a[2];

    const int blk = blockIdx.x, tid = threadIdx.x;
    const int grp = blk & (NGRP - 1);
    const int wv = tid >> 6, lane = tid & 63, ks = lane >> 3, b4 = lane & 7;

    for (int i = tid; i < 512 * 20; i += NT) {
        const int k = i / 20, c = i - k * 20;
        wab_lds[i] = (c < 16) ? Whh[(size_t)k * G4 + blk * 16 + c]
                              : Wdec[(size_t)k * JJ + blk * 4 + (c - 16)];
    }
    for (int i = tid; i < 512 * 12; i += NT) {
        const int k = i / 12, c = i - k * 12;
        wout_lds[i] = (c < 8) ? Wout[(size_t)k * VV + blk * 8 + c] : 0.f;
    }
    float bjr[4];
#pragma unroll
    for (int c = 0; c < 4; ++c) bjr[c] = bj[blk * 4 + c];
    __syncthreads();

    float acc[4][4];
    for (int t = 0; t < TT; ++t) {
        // ======== window A: stage h; Whh (waves 0-3); Wdec K-halves (waves 4-5) -> joint
        {
            float v[16];
#pragma unroll
            for (int p = 0; p < 16; ++p)
                v[p] = __hip_atomic_load(&g_h[tid + p * 1024], RLX, AGT);
#pragma unroll
            for (int p = 0; p < 16; ++p) x_lds[tid + p * 1024] = v[p];
        }
        __syncthreads();
        if (wv < 4) {
            mv4<64>(wab_lds, 20, wv * 4, 0, x_lds, ks, b4, acc);
            if (ks == 0) {
#pragma unroll
                for (int c = 0; c < 4; ++c)
#pragma unroll
                    for (int j = 0; j < 4; ++j)
                        __hip_atomic_store(&g_hW[(size_t)(b4 * 4 + j) * G4 + blk * 16 + wv * 4 + c],
                                           acc[c][j], RLX, AGT);
            }
        } else if (wv < 6) {
            mv4<32>(wab_lds, 20, 16, (wv - 4) * 256, x_lds, ks, b4, acc);
            if (wv == 5 && ks == 0) {
#pragma unroll
                for (int c = 0; c < 4; ++c)
#pragma unroll
                    for (int j = 0; j < 4; ++j)
                        part_lds[c * 33 + b4 * 4 + j] = acc[c][j];
            }
        }
        __syncthreads();
        if (wv == 4 && ks == 0) {
            const float* ep = g_encp + (size_t)t * JJ * BB + (size_t)blk * 4 * BB;
#pragma unroll
            for (int c = 0; c < 4; ++c) {
                const float4 ev = *reinterpret_cast<const float4*>(ep + c * BB + b4 * 4);
                const float evv[4] = { ev.x, ev.y, ev.z, ev.w };
#pragma unroll
                for (int j = 0; j < 4; ++j) {
                    const float u = acc[c][j] + part_lds[c * 33 + b4 * 4 + j] + evv[j] + bjr[c];
                    __hip_atomic_store(&g_joint[(blk * 4 + c) * BB + b4 * 4 + j],
                                       tanhf(u), RLX, AGT);
                }
            }
        }
        gbar_arrive(grp, 0, t + 1);
        gbar_wait(grp, 0, t + 1);

        // ======== window B: stage joint; Wout tiles (waves 0-3) -> logits -> stats
        {
            float v[16];
#pragma unroll
            for (int p = 0; p < 16; ++p)
                v[p] = __hip_atomic_load(&g_joint[tid + p * 1024], RLX, AGT);
#pragma unroll
            for (int p = 0; p < 16; ++p) x_lds[tid + p * 1024] = v[p];
        }
        __syncthreads();
        if (wv < 4) {
            const int tile = wv & 1, kh = wv >> 1;
            mv4<32>(wout_lds, 12, tile * 4, kh * 256, x_lds, ks, b4, acc);
            if (kh == 1 && ks == 0) {
#pragma unroll
                for (int c = 0; c < 4; ++c)
#pragma unroll
                    for (int j = 0; j < 4; ++j)
                        part_lds[tile * 160 + c * 33 + b4 * 4 + j] = acc[c][j];
            }
        }
        __syncthreads();
        if (wv < 2 && ks == 0) {  // combine K-halves, stash logits
#pragma unroll
            for (int c = 0; c < 4; ++c)
#pragma unroll
                for (int j = 0; j < 4; ++j)
                    logit_lds[(wv * 4 + c) * 33 + b4 * 4 + j] =
                        acc[c][j] + part_lds[wv * 160 + c * 33 + b4 * 4 + j];
        }
        __syncthreads();
        if (wv == 0 && lane < BB) {  // per-b stats over this block's 8 cols
            const int b = lane;
            float m = -1e30f; int a = 0;
#pragma unroll
            for (int c = 0; c < 8; ++c) {
                const float l = logit_lds[c * 33 + b];
                if (l > m) { m = l; a = blk * 8 + c; }
            }
            float s = 0.f;
#pragma unroll
            for (int c = 0; c < 8; ++c) s += expf(logit_lds[c * 33 + b] - m);
            __hip_atomic_store(&g_pm[b * NB + blk], m, RLX, AGT);
            __hip_atomic_store(&g_pa[b * NB + blk], a, RLX, AGT);
            __hip_atomic_store(&g_ps[b * NB + blk], s, RLX, AGT);
        }
        gbar_arrive(grp, 1, t + 1);

        // ======== window C: row-blocks reduce stats + LSTM; others fall through
        if (blk < BB) {
            gbar_wait(grp, 1, t + 1);
            const int r = blk;
            float m0 = -1e30f, s_loc = 0.f; int a0 = 1 << 30;
            if (tid < NB) {  // waves 0,1 fully valid
                m0 = __hip_atomic_load(&g_pm[r * NB + tid], RLX, AGT);
                a0 = __hip_atomic_load(&g_pa[r * NB + tid], RLX, AGT);
                s_loc = __hip_atomic_load(&g_ps[r * NB + tid], RLX, AGT);
            }
            float m = m0; int a = a0;
#pragma unroll
            for (int off = 32; off; off >>= 1) {
                const float om = __shfl_xor(m, off, 64);
                const int   oa = __shfl_xor(a, off, 64);
                if (om > m || (om == m && oa < a)) { m = om; a = oa; }
            }
            if (lane == 0 && wv < 2) { red_m[wv] = m; red_a[wv] = a; }
            __syncthreads();
            float M; int P;
            {
                const float ma = red_m[0], mb = red_m[1];
                const int aa = red_a[0], ab = red_a[1];
                if (mb > ma || (mb == ma && ab < aa)) { M = mb; P = ab; }
                else { M = ma; P = aa; }
            }
            float e = (tid < NB) ? s_loc * expf(m0 - M) : 0.f;
#pragma unroll
            for (int off = 32; off; off >>= 1) e += __shfl_xor(e, off, 64);
            if (lane == 0 && wv < 2) red_s[wv] = e;
            __syncthreads();
            if (tid == 0) {
                const float S = red_s[0] + red_s[1];
                out[r * TT + t] = (float)P;
                if (P != 0) g_score[r] += -logf(S);
            }
            if (P != 0 && tid < HH) {
                const int k = tid;
                const float* Ep = g_E + (size_t)P * G4;
                const float hw0 = __hip_atomic_load(&g_hW[(size_t)r * G4 + k],        RLX, AGT);
                const float hw1 = __hip_atomic_load(&g_hW[(size_t)r * G4 + 512 + k],  RLX, AGT);
                const float hw2 = __hip_atomic_load(&g_hW[(size_t)r * G4 + 1024 + k], RLX, AGT);
                const float hw3 = __hip_atomic_load(&g_hW[(size_t)r * G4 + 1536 + k], RLX, AGT);
                const float i_g = Ep[k]        + hw0 + bl[k];
                const float f_g = Ep[512 + k]  + hw1 + bl[512 + k];
                const float g_g = Ep[1024 + k] + hw2 + bl[1024 + k];
                const float o_g = Ep[1536 + k] + hw3 + bl[1536 + k];
                const float si = 1.f / (1.f + expf(-i_g));
                const float sf = 1.f / (1.f + expf(-f_g));
                const float so = 1.f / (1.f + expf(-o_g));
                const float cn = sf * g_c[r * HH + k] + si * tanhf(g_g);
                const float hn = so * tanhf(cn);
                g_c[r * HH + k] = cn;
                __hip_atomic_store(&g_h[k * BB + r], hn, RLX, AGT);
            }
        }
        gbar_arrive(grp, 2, t + 1);
        gbar_wait(grp, 2, t + 1);
    }
}

// ---------------- K4: scores + mean(exp(score)) ----------------
__global__ void k_final(float* __restrict__ out) {
    const int b = threadIdx.x;  // 64 threads
    float e = 0.f;
    if (b < BB) {
        const float sc = g_score[b];
        out[BB * TT + b] = sc;
        e = expf(sc);
    }
#pragma unroll
    for (int off = 32; off; off >>= 1) e += __shfl_xor(e, off, 64);
    if (b == 0) out[BB * TT + BB] = e / (float)BB;
}

extern "C" void kernel_launch(void* const* d_in, const int* in_sizes, int n_in,
                              void* d_out, int out_size, void* d_ws, size_t ws_size,
                              hipStream_t stream) {
    const float* enc  = (const float*)d_in[0];
    const float* emb  = (const float*)d_in[1];
    const float* Wih  = (const float*)d_in[2];
    const float* Whh  = (const float*)d_in[3];
    const float* bl   = (const float*)d_in[4];
    const float* Wenc = (const float*)d_in[5];
    const float* Wdec = (const float*)d_in[6];
    const float* bj   = (const float*)d_in[7];
    const float* Wout = (const float*)d_in[8];
    float* out = (float*)d_out;

    hipLaunchKernelGGL(k_encproj, dim3(TT), dim3(256), 0, stream, enc, Wenc);
    hipLaunchKernelGGL(k_embproj, dim3(128), dim3(256), 0, stream, emb, Wih);
    hipLaunchKernelGGL(k_init, dim3(1), dim3(512), 0, stream, bl);

    void* args[] = { (void*)&Wdec, (void*)&Wout, (void*)&Whh,
                     (void*)&bj, (void*)&bl, (void*)&out };
    hipLaunchCooperativeKernel((const void*)k_loop, dim3(NB), dim3(NT), args, 0, stream);

    hipLaunchKernelGGL(k_final, dim3(1), dim3(64), 0, stream, out);
}